// Round 11
// baseline (448.007 us; speedup 1.0000x reference)
//
#include <hip/hip_runtime.h>
#include <math.h>

typedef short short8 __attribute__((ext_vector_type(8)));
typedef float f32x4 __attribute__((ext_vector_type(4)));

#define BB 32
#define CIN 256
#define COUT 256
#define SPD 64
#define SPP 4096
#define SDIM 256

constexpr float LIN_SCALE  = 0.0625f;                 // 1/sqrt(256)
constexpr float CONV_SCALE = 0.020833333333333332f;   // 1/sqrt(2304)
constexpr float EPS = 1e-6f;

// ---- ws byte-offset layout ----
#define WSB_STYLE   0ULL
#define WSB_DEMOD   32768ULL
#define WSB_WSQ     65536ULL
#define WSB_SP      327680ULL
#define WSB_DSP     851968ULL
#define WSB_ZERO    852096ULL      // 1 KiB of zeros
#define WSB_WT2     860160ULL      // 1,179,648 B bf16 weights [tap][co][ci]
#define WSB_SSQP    2039808ULL     // 32,768 B ssq partials [256][32] f32
#define WSB_XST     2097152ULL     // 67,108,864 B bf16 xs_t [b][p][ci]
#define WS_NEED     (WSB_XST + 67108864ULL)

__device__ inline unsigned short f2bf(float f) {
    unsigned u = __builtin_bit_cast(unsigned, f);
    u = (u + 0x7fffu + ((u >> 16) & 1u)) >> 16;   // RNE
    return (unsigned short)u;
}

// async global->LDS DMA, 16B per lane; LDS dest = wave-uniform base + lane*16
__device__ inline void dma16(const void* g, void* l) {
    __builtin_amdgcn_global_load_lds(
        (const __attribute__((address_space(1))) unsigned int*)g,
        (__attribute__((address_space(3))) unsigned int*)l, 16, 0, 0);
}

// ---------------- prep kernels ----------------

__global__ void k_zero(unsigned* __restrict__ p) {
    p[threadIdx.x] = 0u;   // 256 u32 = 1 KiB
}

__global__ void k_wsq(const float* __restrict__ weight, float* __restrict__ wsq) {
    int co = blockIdx.x, ci = threadIdx.x;
    const float* wp = weight + (co * CIN + ci) * 9;
    float s = 0.f;
#pragma unroll
    for (int t = 0; t < 9; t++) { float v = wp[t]; s += v * v; }
    wsq[co * CIN + ci] = s;
}

// style + demod, coalesced: 4 lanes share one row, shfl_xor reduce.
__global__ __launch_bounds__(256) void k_style(
    const float* __restrict__ style_in,
    const float* __restrict__ mod_w,
    const float* __restrict__ mod_b,
    const float* __restrict__ wsq,
    float* __restrict__ style,
    float* __restrict__ demod) {
    __shared__ float s_in[SDIM];
    __shared__ float s2[CIN];
    int b = blockIdx.x, t = threadIdx.x;
    s_in[t] = style_in[b * 512 + t];
    __syncthreads();
    int kq = t & 3, rr = t >> 2;   // rr 0..63
#pragma unroll
    for (int c = 0; c < 4; c++) {
        int ci = c * 64 + rr;
        const float4* wrow = (const float4*)(mod_w + (size_t)ci * 256 + kq * 64);
        float a = 0.f;
#pragma unroll
        for (int j = 0; j < 16; j++) {
            float4 wv = wrow[j];
            int kb = kq * 64 + j * 4;
            a += s_in[kb] * wv.x + s_in[kb + 1] * wv.y + s_in[kb + 2] * wv.z + s_in[kb + 3] * wv.w;
        }
        a += __shfl_xor(a, 1); a += __shfl_xor(a, 2);
        if (kq == 0) {
            float st = a * LIN_SCALE + mod_b[ci];
            style[b * 256 + ci] = st;
            s2[ci] = st * st;
        }
    }
    __syncthreads();
#pragma unroll
    for (int c = 0; c < 4; c++) {
        int co = c * 64 + rr;
        const float4* wrow = (const float4*)(wsq + (size_t)co * 256 + kq * 64);
        float a = 0.f;
#pragma unroll
        for (int j = 0; j < 16; j++) {
            float4 wv = wrow[j];
            int kb = kq * 64 + j * 4;
            a += s2[kb] * wv.x + s2[kb + 1] * wv.y + s2[kb + 2] * wv.z + s2[kb + 3] * wv.w;
        }
        a += __shfl_xor(a, 1); a += __shfl_xor(a, 2);
        if (kq == 0) demod[b * 256 + co] = rsqrtf(CONV_SCALE * CONV_SCALE * a + EPS);
    }
}

// spatial map, parallel: 256 blocks x 16 p-rows; lanes share sp_w rows
// (broadcast); deterministic per-block partial sums (no atomics).
__global__ __launch_bounds__(256) void k_spatial2(
    const float* __restrict__ style_in,
    const float* __restrict__ sp_w,
    const float* __restrict__ sp_b,
    float* __restrict__ sp,
    float* __restrict__ ssq_part) {
    __shared__ float s_in[32][257];
    __shared__ float sred[256];
    int blk = blockIdx.x, t = threadIdx.x;
    int p0 = blk * 16;
    for (int idx = t; idx < 8192; idx += 256) {
        int b = idx >> 8, k = idx & 255;
        s_in[b][k] = style_in[b * 512 + 256 + k];
    }
    __syncthreads();
    int b = t & 31, pl = t >> 5;      // pl 0..7
    float ss = 0.f;
#pragma unroll
    for (int half = 0; half < 2; half++) {
        int p = p0 + half * 8 + pl;
        const float* wr = sp_w + (size_t)p * 256;
        float a = 0.f;
        for (int k = 0; k < 256; k++) a += s_in[b][k] * wr[k];
        float v = a * LIN_SCALE + sp_b[p];
        sp[b * SPP + p] = v;
        ss += v * v;
    }
    sred[t] = ss;
    __syncthreads();
    if (t < 32) {
        float s = 0.f;
#pragma unroll
        for (int r = 0; r < 8; r++) s += sred[r * 32 + t];
        ssq_part[blk * 32 + t] = s;
    }
}

__global__ void k_dsp(const float* __restrict__ ssq_part, float* __restrict__ dsp) {
    int b = threadIdx.x;   // 32 threads
    float s = 0.f;
    for (int i = 0; i < 256; i++) s += ssq_part[i * 32 + b];
    dsp[b] = sqrtf((float)SPP / s + EPS);
}

// weight [co][ci][tap] fp32 -> wt2[tap][co][ci] bf16 (raw, unscaled)
__global__ void k_wt(const float* __restrict__ weight, unsigned short* __restrict__ wt2) {
    int idx = blockIdx.x * 256 + threadIdx.x;   // grid 2304 -> 589824
    int tap = idx >> 16;
    int r = idx & 65535;
    int co = r >> 8, ci = r & 255;
    wt2[idx] = f2bf(weight[(co * 256 + ci) * 9 + tap]);
}

// x [b][ci][p] fp32 -> xs_t[b][p][ci] bf16 scaled by style[b][ci].
// LDS-tiled transpose, coalesced both sides.
__global__ __launch_bounds__(256) void k_xt(
    const float* __restrict__ x, const float* __restrict__ style,
    unsigned short* __restrict__ xst) {
    __shared__ float tile[64][65];
    int bid = blockIdx.x;
    int b  = (bid & 7) * 4 + ((bid >> 3) & 3);
    int p0 = (bid >> 5) * 64;
    int t = threadIdx.x;
    int w = t >> 6, lane = t & 63;
    int hi = t >> 5, lo = t & 31;

    for (int cc = 0; cc < 4; cc++) {
#pragma unroll
        for (int it = 0; it < 16; it++) {
            int ci_l = it * 4 + w;
            int ci = cc * 64 + ci_l;
            float st = style[b * 256 + ci];
            tile[lane][ci_l] = x[((size_t)(b * 256 + ci)) * SPP + p0 + lane] * st;
        }
        __syncthreads();
#pragma unroll
        for (int it = 0; it < 8; it++) {
            int p_l = it * 8 + hi;
            unsigned pk = (unsigned)f2bf(tile[p_l][lo * 2])
                        | ((unsigned)f2bf(tile[p_l][lo * 2 + 1]) << 16);
            unsigned* dst = (unsigned*)xst + ((size_t)(b * SPP + p0 + p_l)) * 128 + cc * 32 + lo;
            *dst = pk;
        }
        __syncthreads();
    }
}

// ---------------- MFMA conv kernel (occupancy fix: 4 waves/SIMD) ----------
// grid 2048: bid -> [rt(5)][coh(1)][b_lo(2)][xcd(3)], b = xcd*4+b_lo,
// h0 = rt*2, coh = co half. block 256 = 4 waves (2x2): wr=w>>1 -> 64-co
// slab within the 128-co half, wc=w&1 -> row h0+wc (64 p).
// acc = 4x4 f32x4 = 64 AGPRs -> total regs ~120 <= 128 -> 4 waves/SIMD
// (16 waves/CU, 4 blocks/CU). All r5-r10 variants were pinned at ~22%
// MfmaUtil with 2 waves/SIMD regardless of schedule => latency-bound,
// correlated by barriers; this doubles TLP latency hiding and gives 4
// independent blocks/CU to decorrelate the per-kc barrier drains.
// Staging/swizzle/epilogue byte-identical to verified r10.

__global__ __launch_bounds__(256, 4) void k_conv_mfma(
    const unsigned short* __restrict__ xst,
    const unsigned short* __restrict__ wt2,
    const float* __restrict__ demod,
    const float* __restrict__ sp,
    const float* __restrict__ dsp,
    const unsigned short* __restrict__ zeropad,
    float* __restrict__ out)
{
    __shared__ union {
        char stage[2][16896];      // 2 x 264 slots x 64B
        float ep[4][2176];         // 4 waves x 32 rows x 68 floats (34816 B)
    } lds;
    __shared__ float demod_l[256];

    int bid = blockIdx.x;
    int xcd  = bid & 7;
    int b_lo = (bid >> 3) & 3;
    int coh  = (bid >> 5) & 1;
    int rt   = bid >> 6;           // 0..31
    int b  = xcd * 4 + b_lo;
    int h0 = rt * 2;
    int t = threadIdx.x;
    int w = t >> 6, lane = t & 63;
    int wr = w >> 1, wc = w & 1;
    int lcol = lane & 15, kg = lane >> 4;

    demod_l[t] = demod[b * 256 + t];

    const unsigned short* xb = xst + (size_t)b * SPP * 256;

    // per-thread DMA source pointers (kc advances source by 32 elements)
    const unsigned short* sbase[5];
#pragma unroll
    for (int it = 0; it < 5; it++) {
        int idx16 = t + it * 256;
        const unsigned short* s = zeropad;
        if (idx16 < 1056) {
            int slot = idx16 >> 2, j = idx16 & 3;
            int row = slot / 66, col = slot - row * 66;
            int g = j ^ ((slot >> 1) & 3);     // inverse swizzle on source
            int gh = h0 + row - 1, gw = col - 1;
            if ((unsigned)gh < 64u && (unsigned)gw < 64u)
                s = xb + ((size_t)(gh * 64 + gw)) * 256 + g * 8;
        }
        sbase[it] = s;
    }

#define STAGE_DMA(BUF, KC) { _Pragma("unroll") \
    for (int it = 0; it < 4; it++) \
        dma16(sbase[it] + (KC) * 32, &lds.stage[BUF][0] + (t + it * 256) * 16); \
    if (t < 32) dma16(sbase[4] + (KC) * 32, &lds.stage[BUF][0] + (t + 1024) * 16); }

    STAGE_DMA(0, 0);

    f32x4 acc[4][4];
#pragma unroll
    for (int m = 0; m < 4; m++)
#pragma unroll
        for (int n = 0; n < 4; n++) acc[m][n] = (f32x4){0.f, 0.f, 0.f, 0.f};

    const unsigned short* wbase = wt2 + (size_t)(coh * 128 + wr * 64 + lcol) * 256 + kg * 8;
    int cur = 0;
    __syncthreads();   // drain prologue DMA

    for (int kc = 0; kc < 8; kc++) {
        if (kc < 7) STAGE_DMA(cur ^ 1, kc + 1);
        const char* lb = &lds.stage[cur][0];
        const unsigned short* wk = wbase + kc * 32;

#pragma unroll
        for (int tap = 0; tap < 9; tap++) {
            const int dh = tap / 3, dw = tap - dh * 3;
            const unsigned short* wt_ = wk + tap * 65536;
            short8 wA[4];
#pragma unroll
            for (int m = 0; m < 4; m++) wA[m] = *(const short8*)(wt_ + m * 4096);
            int sbase0 = (wc + dh) * 66 + dw + lcol;
            int q = (sbase0 >> 1) & 3;               // n*16 doesn't touch bits 1-2
            const char* lbp = lb + sbase0 * 64 + ((kg ^ q) << 4);
#pragma unroll
            for (int n = 0; n < 4; n++) {
                short8 bv = *(const short8*)(lbp + n * 1024);
#pragma unroll
                for (int m = 0; m < 4; m++)
                    acc[m][n] = __builtin_amdgcn_mfma_f32_16x16x32_bf16(wA[m], bv, acc[m][n], 0, 0, 0);
            }
        }

        __syncthreads();
        cur ^= 1;
    }

    // ---- epilogue: scale, per-wave LDS transpose, coalesced dwordx4 stores ----
    // Per-wave private ep region; within-wave LDS ordering via lgkmcnt;
    // kc loop's final __syncthreads fenced the stage-buffer reuse.
    float dspb = dsp[b];
    int hout = h0 + wc;
    float spn[4];
#pragma unroll
    for (int nn = 0; nn < 4; nn++)
        spn[nn] = sp[b * SPP + hout * 64 + nn * 16 + lcol] * dspb;

    float* ep = &lds.ep[w][0];
#pragma unroll
    for (int ch = 0; ch < 2; ch++) {          // 2 chunks of 32 co
#pragma unroll
        for (int mm = 0; mm < 2; mm++) {
#pragma unroll
            for (int r2 = 0; r2 < 4; r2++) {
                int lr = mm * 16 + kg * 4 + r2;
                float dm = demod_l[coh * 128 + wr * 64 + ch * 32 + lr] * CONV_SCALE;
#pragma unroll
                for (int nn = 0; nn < 4; nn++)
                    ep[lr * 68 + nn * 16 + lcol] =
                        acc[ch * 2 + mm][nn][r2] * dm * spn[nn];
            }
        }
#pragma unroll
        for (int i = 0; i < 8; i++) {
            int lr = i * 4 + kg;
            f32x4 v = *(const f32x4*)(ep + lr * 68 + lcol * 4);
            int co_g = coh * 128 + wr * 64 + ch * 32 + lr;
            *(f32x4*)&out[((size_t)(b * 256 + co_g)) * SPP + hout * 64 + lcol * 4] = v;
        }
    }
}

// ---------------- legacy spatial (fallback path only) ----------------
__global__ void k_spatial(const float* __restrict__ style_in,
                          const float* __restrict__ sp_w,
                          const float* __restrict__ sp_b,
                          float* __restrict__ sp,
                          float* __restrict__ dsp) {
    __shared__ float s_in[SDIM];
    __shared__ float red[256];
    int b = blockIdx.x, t = threadIdx.x;
    s_in[t] = style_in[b * 512 + 256 + t];
    __syncthreads();
    float ss = 0.f;
    for (int i = 0; i < 16; i++) {
        int p = i * 256 + t;
        const float* wr = sp_w + p * SDIM;
        float acc = 0.f;
        for (int k = 0; k < 256; k++) acc += s_in[k] * wr[k];
        float v = acc * LIN_SCALE + sp_b[p];
        sp[b * SPP + p] = v;
        ss += v * v;
    }
    red[t] = ss; __syncthreads();
    for (int o = 128; o > 0; o >>= 1) { if (t < o) red[t] += red[t + o]; __syncthreads(); }
    if (t == 0) dsp[b] = sqrtf((float)SPP / red[0] + EPS);
}

// ---------------- fp32 fallback conv (round-1, known-good) ----------------

#define COTILE 16
#define TS 32
#define HALO 34
#define XS 36

__global__ __launch_bounds__(256) void k_conv_f32(
    const float* __restrict__ x, const float* __restrict__ weight,
    const float* __restrict__ style, const float* __restrict__ demod,
    const float* __restrict__ sp, const float* __restrict__ dsp,
    float* __restrict__ out) {
    __shared__ float xt[HALO * XS];
    __shared__ float wl[COTILE * 12];
    __shared__ float dml[COTILE];

    int bid = blockIdx.x;
    int tile = bid & 3;
    int cot = (bid >> 2) & 15;
    int b = bid >> 6;
    int h0 = (tile >> 1) * TS, w0 = (tile & 1) * TS;
    int t = threadIdx.x;
    int r = t >> 3;
    int cb = (t & 7) * 4;

    if (t < COTILE) dml[t] = demod[b * COUT + cot * COTILE + t];

    float acc[COTILE][4];
#pragma unroll
    for (int co = 0; co < COTILE; co++)
#pragma unroll
        for (int c = 0; c < 4; c++) acc[co][c] = 0.f;

    const float* xb = x + (size_t)b * CIN * SPP;
    const float* stb = style + b * CIN;

    for (int ci = 0; ci < CIN; ci++) {
        __syncthreads();
        const float* xc = xb + ci * SPP;
        for (int idx = t; idx < HALO * HALO; idx += 256) {
            int i = idx / HALO, j = idx - i * HALO;
            int h = h0 + i - 1, wv2 = w0 + j - 1;
            float v = 0.f;
            if ((unsigned)h < SPD && (unsigned)wv2 < SPD) v = xc[h * SPD + wv2];
            xt[i * XS + j] = v;
        }
        if (t < COTILE * 9) {
            int co = t / 9, tap = t - co * 9;
            float wv = weight[((cot * COTILE + co) * CIN + ci) * 9 + tap];
            wl[co * 12 + tap] = wv * (CONV_SCALE * stb[ci]) * dml[co];
        }
        __syncthreads();

        float xv[3][6];
#pragma unroll
        for (int dh = 0; dh < 3; dh++)
#pragma unroll
            for (int jj = 0; jj < 6; jj++)
                xv[dh][jj] = xt[(r + dh) * XS + cb + jj];

#pragma unroll
        for (int co = 0; co < COTILE; co++) {
            float w9[9];
#pragma unroll
            for (int q = 0; q < 9; q++) w9[q] = wl[co * 12 + q];
#pragma unroll
            for (int c = 0; c < 4; c++) {
                float a = acc[co][c];
#pragma unroll
                for (int dh = 0; dh < 3; dh++)
#pragma unroll
                    for (int dw = 0; dw < 3; dw++)
                        a += w9[dh * 3 + dw] * xv[dh][c + dw];
                acc[co][c] = a;
            }
        }
    }

    float dspb = dsp[b];
    int hh = h0 + r, ww = w0 + cb;
    const float* spb = sp + b * SPP + hh * SPD + ww;
    float m[4];
#pragma unroll
    for (int c = 0; c < 4; c++) m[c] = spb[c] * dspb;
#pragma unroll
    for (int co = 0; co < COTILE; co++) {
        float4 v = make_float4(acc[co][0] * m[0], acc[co][1] * m[1],
                               acc[co][2] * m[2], acc[co][3] * m[3]);
        *(float4*)&out[(size_t)((b * COUT + cot * COTILE + co) * SPP) + hh * SPD + ww] = v;
    }
}

// ---------------- launcher ----------------

extern "C" void kernel_launch(void* const* d_in, const int* in_sizes, int n_in,
                              void* d_out, int out_size, void* d_ws, size_t ws_size,
                              hipStream_t stream) {
    const float* x        = (const float*)d_in[0];
    const float* style_in = (const float*)d_in[1];
    const float* weight   = (const float*)d_in[2];
    const float* mod_w    = (const float*)d_in[3];
    const float* mod_b    = (const float*)d_in[4];
    const float* sp_w     = (const float*)d_in[5];
    const float* sp_b     = (const float*)d_in[6];
    float* out = (float*)d_out;
    char* wsb = (char*)d_ws;

    float* style = (float*)(wsb + WSB_STYLE);
    float* demod = (float*)(wsb + WSB_DEMOD);
    float* wsq   = (float*)(wsb + WSB_WSQ);
    float* sp    = (float*)(wsb + WSB_SP);
    float* dsp   = (float*)(wsb + WSB_DSP);
    float* ssqp  = (float*)(wsb + WSB_SSQP);
    unsigned short* wt2 = (unsigned short*)(wsb + WSB_WT2);
    unsigned short* xst = (unsigned short*)(wsb + WSB_XST);

    hipLaunchKernelGGL(k_zero, dim3(1), dim3(256), 0, stream, (unsigned*)(wsb + WSB_ZERO));
    hipLaunchKernelGGL(k_wsq, dim3(COUT), dim3(CIN), 0, stream, weight, wsq);
    hipLaunchKernelGGL(k_style, dim3(BB), dim3(256), 0, stream,
                       style_in, mod_w, mod_b, wsq, style, demod);

    if (ws_size >= WS_NEED) {
        hipLaunchKernelGGL(k_spatial2, dim3(256), dim3(256), 0, stream,
                           style_in, sp_w, sp_b, sp, ssqp);
        hipLaunchKernelGGL(k_dsp, dim3(1), dim3(32), 0, stream, ssqp, dsp);
        hipLaunchKernelGGL(k_wt, dim3(2304), dim3(256), 0, stream, weight, wt2);
        hipLaunchKernelGGL(k_xt, dim3(2048), dim3(256), 0, stream, x, style, xst);
        hipLaunchKernelGGL(k_conv_mfma, dim3(2048), dim3(256), 0, stream,
                           xst, wt2, demod, sp, dsp,
                           (const unsigned short*)(wsb + WSB_ZERO), out);
    } else {
        hipLaunchKernelGGL(k_spatial, dim3(BB), dim3(256), 0, stream,
                           style_in, sp_w, sp_b, sp, dsp);
        hipLaunchKernelGGL(k_conv_f32, dim3(2048), dim3(256), 0, stream,
                           x, weight, style, demod, sp, dsp, out);
    }
}

// Round 12
// 285.320 us; speedup vs baseline: 1.5702x; 1.5702x over previous
//
#include <hip/hip_runtime.h>
#include <math.h>

typedef short short8 __attribute__((ext_vector_type(8)));
typedef float f32x4 __attribute__((ext_vector_type(4)));

#define BB 32
#define CIN 256
#define COUT 256
#define SPD 64
#define SPP 4096
#define SDIM 256

constexpr float LIN_SCALE  = 0.0625f;                 // 1/sqrt(256)
constexpr float CONV_SCALE = 0.020833333333333332f;   // 1/sqrt(2304)
constexpr float EPS = 1e-6f;

// ---- ws byte-offset layout ----
#define WSB_STYLE   0ULL
#define WSB_DEMOD   32768ULL
#define WSB_WSQ     65536ULL
#define WSB_SP      327680ULL
#define WSB_DSP     851968ULL
#define WSB_ZERO    852096ULL      // 1 KiB of zeros
#define WSB_WT2     860160ULL      // 1,179,648 B bf16 weights [kc][tap][cog][lane][8]
#define WSB_SSQP    2039808ULL     // 32,768 B ssq partials [256][32] f32
#define WSB_XST     2097152ULL     // 67,108,864 B bf16 xs_t [b][p][ci]
#define WS_NEED     (WSB_XST + 67108864ULL)

__device__ inline unsigned short f2bf(float f) {
    unsigned u = __builtin_bit_cast(unsigned, f);
    u = (u + 0x7fffu + ((u >> 16) & 1u)) >> 16;   // RNE
    return (unsigned short)u;
}

// async global->LDS DMA, 16B per lane; LDS dest = wave-uniform base + lane*16
__device__ inline void dma16(const void* g, void* l) {
    __builtin_amdgcn_global_load_lds(
        (const __attribute__((address_space(1))) unsigned int*)g,
        (__attribute__((address_space(3))) unsigned int*)l, 16, 0, 0);
}

// ---------------- prep kernels ----------------

__global__ void k_zero(unsigned* __restrict__ p) {
    p[threadIdx.x] = 0u;   // 256 u32 = 1 KiB
}

__global__ void k_wsq(const float* __restrict__ weight, float* __restrict__ wsq) {
    int co = blockIdx.x, ci = threadIdx.x;
    const float* wp = weight + (co * CIN + ci) * 9;
    float s = 0.f;
#pragma unroll
    for (int t = 0; t < 9; t++) { float v = wp[t]; s += v * v; }
    wsq[co * CIN + ci] = s;
}

// style + demod, coalesced: 4 lanes share one row, shfl_xor reduce.
__global__ __launch_bounds__(256) void k_style(
    const float* __restrict__ style_in,
    const float* __restrict__ mod_w,
    const float* __restrict__ mod_b,
    const float* __restrict__ wsq,
    float* __restrict__ style,
    float* __restrict__ demod) {
    __shared__ float s_in[SDIM];
    __shared__ float s2[CIN];
    int b = blockIdx.x, t = threadIdx.x;
    s_in[t] = style_in[b * 512 + t];
    __syncthreads();
    int kq = t & 3, rr = t >> 2;   // rr 0..63
#pragma unroll
    for (int c = 0; c < 4; c++) {
        int ci = c * 64 + rr;
        const float4* wrow = (const float4*)(mod_w + (size_t)ci * 256 + kq * 64);
        float a = 0.f;
#pragma unroll
        for (int j = 0; j < 16; j++) {
            float4 wv = wrow[j];
            int kb = kq * 64 + j * 4;
            a += s_in[kb] * wv.x + s_in[kb + 1] * wv.y + s_in[kb + 2] * wv.z + s_in[kb + 3] * wv.w;
        }
        a += __shfl_xor(a, 1); a += __shfl_xor(a, 2);
        if (kq == 0) {
            float st = a * LIN_SCALE + mod_b[ci];
            style[b * 256 + ci] = st;
            s2[ci] = st * st;
        }
    }
    __syncthreads();
#pragma unroll
    for (int c = 0; c < 4; c++) {
        int co = c * 64 + rr;
        const float4* wrow = (const float4*)(wsq + (size_t)co * 256 + kq * 64);
        float a = 0.f;
#pragma unroll
        for (int j = 0; j < 16; j++) {
            float4 wv = wrow[j];
            int kb = kq * 64 + j * 4;
            a += s2[kb] * wv.x + s2[kb + 1] * wv.y + s2[kb + 2] * wv.z + s2[kb + 3] * wv.w;
        }
        a += __shfl_xor(a, 1); a += __shfl_xor(a, 2);
        if (kq == 0) demod[b * 256 + co] = rsqrtf(CONV_SCALE * CONV_SCALE * a + EPS);
    }
}

// spatial map, parallel: 256 blocks x 16 p-rows; lanes share sp_w rows
// (broadcast); deterministic per-block partial sums (no atomics).
__global__ __launch_bounds__(256) void k_spatial2(
    const float* __restrict__ style_in,
    const float* __restrict__ sp_w,
    const float* __restrict__ sp_b,
    float* __restrict__ sp,
    float* __restrict__ ssq_part) {
    __shared__ float s_in[32][257];
    __shared__ float sred[256];
    int blk = blockIdx.x, t = threadIdx.x;
    int p0 = blk * 16;
    for (int idx = t; idx < 8192; idx += 256) {
        int b = idx >> 8, k = idx & 255;
        s_in[b][k] = style_in[b * 512 + 256 + k];
    }
    __syncthreads();
    int b = t & 31, pl = t >> 5;      // pl 0..7
    float ss = 0.f;
#pragma unroll
    for (int half = 0; half < 2; half++) {
        int p = p0 + half * 8 + pl;
        const float* wr = sp_w + (size_t)p * 256;
        float a = 0.f;
        for (int k = 0; k < 256; k++) a += s_in[b][k] * wr[k];
        float v = a * LIN_SCALE + sp_b[p];
        sp[b * SPP + p] = v;
        ss += v * v;
    }
    sred[t] = ss;
    __syncthreads();
    if (t < 32) {
        float s = 0.f;
#pragma unroll
        for (int r = 0; r < 8; r++) s += sred[r * 32 + t];
        ssq_part[blk * 32 + t] = s;
    }
}

__global__ void k_dsp(const float* __restrict__ ssq_part, float* __restrict__ dsp) {
    int b = threadIdx.x;   // 32 threads
    float s = 0.f;
    for (int i = 0; i < 256; i++) s += ssq_part[i * 32 + b];
    dsp[b] = sqrtf((float)SPP / s + EPS);
}

// weight [co][ci][tap] fp32 -> wt4 fragment-contiguous bf16:
// [kc 8][tap 9][cog 16][lane 64][e 8], lane = kg*16+lcol:
//   co = cog*16 + (lane&15), ci = kc*32 + (lane>>4)*8 + e.
// A wave's A-fragment load (one cog) is then lane*16B CONTIGUOUS (1 KB,
// 8 fully-used lines) vs the old [tap][co][ci] scatter (16 half-used lines).
__global__ void k_wt(const float* __restrict__ weight, unsigned short* __restrict__ wt4) {
    int idx = blockIdx.x * 256 + threadIdx.x;   // grid 2304 -> 589824
    int e    = idx & 7;
    int r1   = idx >> 3;
    int lane = r1 & 63;
    int r2   = r1 >> 6;
    int cog  = r2 & 15;
    int r3   = r2 >> 4;       // 0..71
    int tap  = r3 % 9;
    int kc   = r3 / 9;
    int co = cog * 16 + (lane & 15);
    int ci = kc * 32 + (lane >> 4) * 8 + e;
    wt4[idx] = f2bf(weight[(co * 256 + ci) * 9 + tap]);
}

// x [b][ci][p] fp32 -> xs_t[b][p][ci] bf16 scaled by style[b][ci].
// LDS-tiled transpose, coalesced both sides.
__global__ __launch_bounds__(256) void k_xt(
    const float* __restrict__ x, const float* __restrict__ style,
    unsigned short* __restrict__ xst) {
    __shared__ float tile[64][65];
    int bid = blockIdx.x;
    int b  = (bid & 7) * 4 + ((bid >> 3) & 3);
    int p0 = (bid >> 5) * 64;
    int t = threadIdx.x;
    int w = t >> 6, lane = t & 63;
    int hi = t >> 5, lo = t & 31;

    for (int cc = 0; cc < 4; cc++) {
#pragma unroll
        for (int it = 0; it < 16; it++) {
            int ci_l = it * 4 + w;
            int ci = cc * 64 + ci_l;
            float st = style[b * 256 + ci];
            tile[lane][ci_l] = x[((size_t)(b * 256 + ci)) * SPP + p0 + lane] * st;
        }
        __syncthreads();
#pragma unroll
        for (int it = 0; it < 8; it++) {
            int p_l = it * 8 + hi;
            unsigned pk = (unsigned)f2bf(tile[p_l][lo * 2])
                        | ((unsigned)f2bf(tile[p_l][lo * 2 + 1]) << 16);
            unsigned* dst = (unsigned*)xst + ((size_t)(b * SPP + p0 + p_l)) * 128 + cc * 32 + lo;
            *dst = pk;
        }
        __syncthreads();
    }
}

// ---------------- MFMA conv kernel (coalesced bulk weight preload) --------
// grid 2048: bid -> [rt(5)][coh(1)][b_lo(2)][xcd(3)], b = xcd*4+b_lo,
// h0 = rt*2. block 256 = 4 waves (2x2): wr=w>>1 -> 64-co slab within the
// 128-co half, wc=w&1 -> row h0+wc (64 p). acc = 64 AGPRs.
// Per kc: ALL 36 weight fragments preloaded into 144 VGPRs via wt4's
// lane-contiguous layout (one coalesced 1KB load each, issued back-to-back
// BEFORE the x-DMAs so the counted vmcnt wait for weights never drains
// DMAs), then an unbroken 144-MFMA burst. launch_bounds(256,2) -> 256-reg
// cap (2 waves/SIMD): ILP replaces TLP (r11 proved 4 waves/SIMD doesn't
// help; r6-r11 were issue-serialized on scattered weight loads).

__global__ __launch_bounds__(256, 2) void k_conv_mfma(
    const unsigned short* __restrict__ xst,
    const unsigned short* __restrict__ wt4,
    const float* __restrict__ demod,
    const float* __restrict__ sp,
    const float* __restrict__ dsp,
    const unsigned short* __restrict__ zeropad,
    float* __restrict__ out)
{
    __shared__ union {
        char stage[2][16896];      // 2 x 264 slots x 64B
        float ep[4][2176];         // 4 waves x 32 rows x 68 floats (34816 B)
    } lds;
    __shared__ float demod_l[256];

    int bid = blockIdx.x;
    int xcd  = bid & 7;
    int b_lo = (bid >> 3) & 3;
    int coh  = (bid >> 5) & 1;
    int rt   = bid >> 6;           // 0..31
    int b  = xcd * 4 + b_lo;
    int h0 = rt * 2;
    int t = threadIdx.x;
    int w = t >> 6, lane = t & 63;
    int wr = w >> 1, wc = w & 1;
    int lcol = lane & 15, kg = lane >> 4;
    int cog0 = coh * 8 + wr * 4;   // first co-group (of 16) for this wave

    demod_l[t] = demod[b * 256 + t];

    const unsigned short* xb = xst + (size_t)b * SPP * 256;

    // per-thread DMA source pointers (kc advances source by 32 elements)
    const unsigned short* sbase[5];
#pragma unroll
    for (int it = 0; it < 5; it++) {
        int idx16 = t + it * 256;
        const unsigned short* s = zeropad;
        if (idx16 < 1056) {
            int slot = idx16 >> 2, j = idx16 & 3;
            int row = slot / 66, col = slot - row * 66;
            int g = j ^ ((slot >> 1) & 3);     // inverse swizzle on source
            int gh = h0 + row - 1, gw = col - 1;
            if ((unsigned)gh < 64u && (unsigned)gw < 64u)
                s = xb + ((size_t)(gh * 64 + gw)) * 256 + g * 8;
        }
        sbase[it] = s;
    }

#define STAGE_DMA(BUF, KC) { _Pragma("unroll") \
    for (int it = 0; it < 4; it++) \
        dma16(sbase[it] + (KC) * 32, &lds.stage[BUF][0] + (t + it * 256) * 16); \
    if (t < 32) dma16(sbase[4] + (KC) * 32, &lds.stage[BUF][0] + (t + 1024) * 16); }

    STAGE_DMA(0, 0);

    f32x4 acc[4][4];
#pragma unroll
    for (int m = 0; m < 4; m++)
#pragma unroll
        for (int n = 0; n < 4; n++) acc[m][n] = (f32x4){0.f, 0.f, 0.f, 0.f};

    int cur = 0;
    __syncthreads();   // drain prologue DMA

    for (int kc = 0; kc < 8; kc++) {
        // ---- bulk weight preload: 36 coalesced 1KB loads, oldest in queue ----
        short8 wreg[9][4];
        {
            const unsigned short* wkc = wt4 + (size_t)(kc * 9) * 8192;  // 9 tap-panes of 8192 elems
#pragma unroll
            for (int tap = 0; tap < 9; tap++)
#pragma unroll
                for (int m = 0; m < 4; m++)
                    wreg[tap][m] = *(const short8*)(wkc + (size_t)(tap * 16 + cog0 + m) * 512 + lane * 8);
        }
        if (kc < 7) STAGE_DMA(cur ^ 1, kc + 1);   // younger than all weight loads
        const char* lb = &lds.stage[cur][0];

#pragma unroll
        for (int tap = 0; tap < 9; tap++) {
            const int dh = tap / 3, dw = tap - dh * 3;
            int sbase0 = (wc + dh) * 66 + dw + lcol;
            int q = (sbase0 >> 1) & 3;               // n*16 doesn't touch bits 1-2
            const char* lbp = lb + sbase0 * 64 + ((kg ^ q) << 4);
#pragma unroll
            for (int n = 0; n < 4; n++) {
                short8 bv = *(const short8*)(lbp + n * 1024);
#pragma unroll
                for (int m = 0; m < 4; m++)
                    acc[m][n] = __builtin_amdgcn_mfma_f32_16x16x32_bf16(wreg[tap][m], bv, acc[m][n], 0, 0, 0);
            }
        }

        __syncthreads();
        cur ^= 1;
    }

    // ---- epilogue: scale, per-wave LDS transpose, coalesced dwordx4 stores ----
    float dspb = dsp[b];
    int hout = h0 + wc;
    float spn[4];
#pragma unroll
    for (int nn = 0; nn < 4; nn++)
        spn[nn] = sp[b * SPP + hout * 64 + nn * 16 + lcol] * dspb;

    float* ep = &lds.ep[w][0];
#pragma unroll
    for (int ch = 0; ch < 2; ch++) {          // 2 chunks of 32 co
#pragma unroll
        for (int mm = 0; mm < 2; mm++) {
#pragma unroll
            for (int r2 = 0; r2 < 4; r2++) {
                int lr = mm * 16 + kg * 4 + r2;
                float dm = demod_l[coh * 128 + wr * 64 + ch * 32 + lr] * CONV_SCALE;
#pragma unroll
                for (int nn = 0; nn < 4; nn++)
                    ep[lr * 68 + nn * 16 + lcol] =
                        acc[ch * 2 + mm][nn][r2] * dm * spn[nn];
            }
        }
#pragma unroll
        for (int i = 0; i < 8; i++) {
            int lr = i * 4 + kg;
            f32x4 v = *(const f32x4*)(ep + lr * 68 + lcol * 4);
            int co_g = coh * 128 + wr * 64 + ch * 32 + lr;
            *(f32x4*)&out[((size_t)(b * 256 + co_g)) * SPP + hout * 64 + lcol * 4] = v;
        }
    }
}

// ---------------- legacy spatial (fallback path only) ----------------
__global__ void k_spatial(const float* __restrict__ style_in,
                          const float* __restrict__ sp_w,
                          const float* __restrict__ sp_b,
                          float* __restrict__ sp,
                          float* __restrict__ dsp) {
    __shared__ float s_in[SDIM];
    __shared__ float red[256];
    int b = blockIdx.x, t = threadIdx.x;
    s_in[t] = style_in[b * 512 + 256 + t];
    __syncthreads();
    float ss = 0.f;
    for (int i = 0; i < 16; i++) {
        int p = i * 256 + t;
        const float* wr = sp_w + p * SDIM;
        float acc = 0.f;
        for (int k = 0; k < 256; k++) acc += s_in[k] * wr[k];
        float v = acc * LIN_SCALE + sp_b[p];
        sp[b * SPP + p] = v;
        ss += v * v;
    }
    red[t] = ss; __syncthreads();
    for (int o = 128; o > 0; o >>= 1) { if (t < o) red[t] += red[t + o]; __syncthreads(); }
    if (t == 0) dsp[b] = sqrtf((float)SPP / red[0] + EPS);
}

// ---------------- fp32 fallback conv (round-1, known-good) ----------------

#define COTILE 16
#define TS 32
#define HALO 34
#define XS 36

__global__ __launch_bounds__(256) void k_conv_f32(
    const float* __restrict__ x, const float* __restrict__ weight,
    const float* __restrict__ style, const float* __restrict__ demod,
    const float* __restrict__ sp, const float* __restrict__ dsp,
    float* __restrict__ out) {
    __shared__ float xt[HALO * XS];
    __shared__ float wl[COTILE * 12];
    __shared__ float dml[COTILE];

    int bid = blockIdx.x;
    int tile = bid & 3;
    int cot = (bid >> 2) & 15;
    int b = bid >> 6;
    int h0 = (tile >> 1) * TS, w0 = (tile & 1) * TS;
    int t = threadIdx.x;
    int r = t >> 3;
    int cb = (t & 7) * 4;

    if (t < COTILE) dml[t] = demod[b * COUT + cot * COTILE + t];

    float acc[COTILE][4];
#pragma unroll
    for (int co = 0; co < COTILE; co++)
#pragma unroll
        for (int c = 0; c < 4; c++) acc[co][c] = 0.f;

    const float* xb = x + (size_t)b * CIN * SPP;
    const float* stb = style + b * CIN;

    for (int ci = 0; ci < CIN; ci++) {
        __syncthreads();
        const float* xc = xb + ci * SPP;
        for (int idx = t; idx < HALO * HALO; idx += 256) {
            int i = idx / HALO, j = idx - i * HALO;
            int h = h0 + i - 1, wv2 = w0 + j - 1;
            float v = 0.f;
            if ((unsigned)h < SPD && (unsigned)wv2 < SPD) v = xc[h * SPD + wv2];
            xt[i * XS + j] = v;
        }
        if (t < COTILE * 9) {
            int co = t / 9, tap = t - co * 9;
            float wv = weight[((cot * COTILE + co) * CIN + ci) * 9 + tap];
            wl[co * 12 + tap] = wv * (CONV_SCALE * stb[ci]) * dml[co];
        }
        __syncthreads();

        float xv[3][6];
#pragma unroll
        for (int dh = 0; dh < 3; dh++)
#pragma unroll
            for (int jj = 0; jj < 6; jj++)
                xv[dh][jj] = xt[(r + dh) * XS + cb + jj];

#pragma unroll
        for (int co = 0; co < COTILE; co++) {
            float w9[9];
#pragma unroll
            for (int q = 0; q < 9; q++) w9[q] = wl[co * 12 + q];
#pragma unroll
            for (int c = 0; c < 4; c++) {
                float a = acc[co][c];
#pragma unroll
                for (int dh = 0; dh < 3; dh++)
#pragma unroll
                    for (int dw = 0; dw < 3; dw++)
                        a += w9[dh * 3 + dw] * xv[dh][c + dw];
                acc[co][c] = a;
            }
        }
    }

    float dspb = dsp[b];
    int hh = h0 + r, ww = w0 + cb;
    const float* spb = sp + b * SPP + hh * SPD + ww;
    float m[4];
#pragma unroll
    for (int c = 0; c < 4; c++) m[c] = spb[c] * dspb;
#pragma unroll
    for (int co = 0; co < COTILE; co++) {
        float4 v = make_float4(acc[co][0] * m[0], acc[co][1] * m[1],
                               acc[co][2] * m[2], acc[co][3] * m[3]);
        *(float4*)&out[(size_t)((b * COUT + cot * COTILE + co) * SPP) + hh * SPD + ww] = v;
    }
}

// ---------------- launcher ----------------

extern "C" void kernel_launch(void* const* d_in, const int* in_sizes, int n_in,
                              void* d_out, int out_size, void* d_ws, size_t ws_size,
                              hipStream_t stream) {
    const float* x        = (const float*)d_in[0];
    const float* style_in = (const float*)d_in[1];
    const float* weight   = (const float*)d_in[2];
    const float* mod_w    = (const float*)d_in[3];
    const float* mod_b    = (const float*)d_in[4];
    const float* sp_w     = (const float*)d_in[5];
    const float* sp_b     = (const float*)d_in[6];
    float* out = (float*)d_out;
    char* wsb = (char*)d_ws;

    float* style = (float*)(wsb + WSB_STYLE);
    float* demod = (float*)(wsb + WSB_DEMOD);
    float* wsq   = (float*)(wsb + WSB_WSQ);
    float* sp    = (float*)(wsb + WSB_SP);
    float* dsp   = (float*)(wsb + WSB_DSP);
    float* ssqp  = (float*)(wsb + WSB_SSQP);
    unsigned short* wt4 = (unsigned short*)(wsb + WSB_WT2);
    unsigned short* xst = (unsigned short*)(wsb + WSB_XST);

    hipLaunchKernelGGL(k_zero, dim3(1), dim3(256), 0, stream, (unsigned*)(wsb + WSB_ZERO));
    hipLaunchKernelGGL(k_wsq, dim3(COUT), dim3(CIN), 0, stream, weight, wsq);
    hipLaunchKernelGGL(k_style, dim3(BB), dim3(256), 0, stream,
                       style_in, mod_w, mod_b, wsq, style, demod);

    if (ws_size >= WS_NEED) {
        hipLaunchKernelGGL(k_spatial2, dim3(256), dim3(256), 0, stream,
                           style_in, sp_w, sp_b, sp, ssqp);
        hipLaunchKernelGGL(k_dsp, dim3(1), dim3(32), 0, stream, ssqp, dsp);
        hipLaunchKernelGGL(k_wt, dim3(2304), dim3(256), 0, stream, weight, wt4);
        hipLaunchKernelGGL(k_xt, dim3(2048), dim3(256), 0, stream, x, style, xst);
        hipLaunchKernelGGL(k_conv_mfma, dim3(2048), dim3(256), 0, stream,
                           xst, wt4, demod, sp, dsp,
                           (const unsigned short*)(wsb + WSB_ZERO), out);
    } else {
        hipLaunchKernelGGL(k_spatial, dim3(BB), dim3(256), 0, stream,
                           style_in, sp_w, sp_b, sp, dsp);
        hipLaunchKernelGGL(k_conv_f32, dim3(2048), dim3(256), 0, stream,
                           x, weight, style, demod, sp, dsp, out);
    }
}

// Round 13
// 281.204 us; speedup vs baseline: 1.5932x; 1.0146x over previous
//
#include <hip/hip_runtime.h>
#include <math.h>

typedef short short8 __attribute__((ext_vector_type(8)));
typedef float f32x4 __attribute__((ext_vector_type(4)));

#define BB 32
#define CIN 256
#define COUT 256
#define SPD 64
#define SPP 4096
#define SDIM 256

constexpr float LIN_SCALE  = 0.0625f;                 // 1/sqrt(256)
constexpr float CONV_SCALE = 0.020833333333333332f;   // 1/sqrt(2304)
constexpr float EPS = 1e-6f;

// ---- ws byte-offset layout ----
#define WSB_STYLE   0ULL
#define WSB_DEMOD   32768ULL
#define WSB_WSQ     65536ULL
#define WSB_SP      327680ULL
#define WSB_DSP     851968ULL
#define WSB_ZERO    852096ULL      // 1 KiB of zeros
#define WSB_WT2     860160ULL      // 1,179,648 B bf16 weights [kc][tap][cog][lane][8]
#define WSB_SSQP    2039808ULL     // 32,768 B ssq partials [256][32] f32
#define WSB_XST     2097152ULL     // 67,108,864 B bf16 xs_t [b][p][ci]
#define WS_NEED     (WSB_XST + 67108864ULL)

__device__ inline unsigned short f2bf(float f) {
    unsigned u = __builtin_bit_cast(unsigned, f);
    u = (u + 0x7fffu + ((u >> 16) & 1u)) >> 16;   // RNE
    return (unsigned short)u;
}

// async global->LDS DMA, 16B per lane; LDS dest = wave-uniform base + lane*16
__device__ inline void dma16(const void* g, void* l) {
    __builtin_amdgcn_global_load_lds(
        (const __attribute__((address_space(1))) unsigned int*)g,
        (__attribute__((address_space(3))) unsigned int*)l, 16, 0, 0);
}

// ---------------- prep kernels ----------------

// wsq (+ zeropad fill by block 0)
__global__ void k_wsq(const float* __restrict__ weight, float* __restrict__ wsq,
                      unsigned* __restrict__ zero) {
    int co = blockIdx.x, ci = threadIdx.x;
    if (co == 0) zero[ci] = 0u;    // 256 u32 = 1 KiB
    const float* wp = weight + (co * CIN + ci) * 9;
    float s = 0.f;
#pragma unroll
    for (int t = 0; t < 9; t++) { float v = wp[t]; s += v * v; }
    wsq[co * CIN + ci] = s;
}

// style + demod, coalesced: 4 lanes share one row, shfl_xor reduce.
__global__ __launch_bounds__(256) void k_style(
    const float* __restrict__ style_in,
    const float* __restrict__ mod_w,
    const float* __restrict__ mod_b,
    const float* __restrict__ wsq,
    float* __restrict__ style,
    float* __restrict__ demod) {
    __shared__ float s_in[SDIM];
    __shared__ float s2[CIN];
    int b = blockIdx.x, t = threadIdx.x;
    s_in[t] = style_in[b * 512 + t];
    __syncthreads();
    int kq = t & 3, rr = t >> 2;   // rr 0..63
#pragma unroll
    for (int c = 0; c < 4; c++) {
        int ci = c * 64 + rr;
        const float4* wrow = (const float4*)(mod_w + (size_t)ci * 256 + kq * 64);
        float a = 0.f;
#pragma unroll
        for (int j = 0; j < 16; j++) {
            float4 wv = wrow[j];
            int kb = kq * 64 + j * 4;
            a += s_in[kb] * wv.x + s_in[kb + 1] * wv.y + s_in[kb + 2] * wv.z + s_in[kb + 3] * wv.w;
        }
        a += __shfl_xor(a, 1); a += __shfl_xor(a, 2);
        if (kq == 0) {
            float st = a * LIN_SCALE + mod_b[ci];
            style[b * 256 + ci] = st;
            s2[ci] = st * st;
        }
    }
    __syncthreads();
#pragma unroll
    for (int c = 0; c < 4; c++) {
        int co = c * 64 + rr;
        const float4* wrow = (const float4*)(wsq + (size_t)co * 256 + kq * 64);
        float a = 0.f;
#pragma unroll
        for (int j = 0; j < 16; j++) {
            float4 wv = wrow[j];
            int kb = kq * 64 + j * 4;
            a += s2[kb] * wv.x + s2[kb + 1] * wv.y + s2[kb + 2] * wv.z + s2[kb + 3] * wv.w;
        }
        a += __shfl_xor(a, 1); a += __shfl_xor(a, 2);
        if (kq == 0) demod[b * 256 + co] = rsqrtf(CONV_SCALE * CONV_SCALE * a + EPS);
    }
}

// spatial map, parallel: 256 blocks x 16 p-rows; lanes share sp_w rows
// (broadcast); deterministic per-block partial sums (no atomics).
__global__ __launch_bounds__(256) void k_spatial2(
    const float* __restrict__ style_in,
    const float* __restrict__ sp_w,
    const float* __restrict__ sp_b,
    float* __restrict__ sp,
    float* __restrict__ ssq_part) {
    __shared__ float s_in[32][257];
    __shared__ float sred[256];
    int blk = blockIdx.x, t = threadIdx.x;
    int p0 = blk * 16;
    for (int idx = t; idx < 8192; idx += 256) {
        int b = idx >> 8, k = idx & 255;
        s_in[b][k] = style_in[b * 512 + 256 + k];
    }
    __syncthreads();
    int b = t & 31, pl = t >> 5;      // pl 0..7
    float ss = 0.f;
#pragma unroll
    for (int half = 0; half < 2; half++) {
        int p = p0 + half * 8 + pl;
        const float* wr = sp_w + (size_t)p * 256;
        float a = 0.f;
        for (int k = 0; k < 256; k++) a += s_in[b][k] * wr[k];
        float v = a * LIN_SCALE + sp_b[p];
        sp[b * SPP + p] = v;
        ss += v * v;
    }
    sred[t] = ss;
    __syncthreads();
    if (t < 32) {
        float s = 0.f;
#pragma unroll
        for (int r = 0; r < 8; r++) s += sred[r * 32 + t];
        ssq_part[blk * 32 + t] = s;
    }
}

__global__ void k_dsp(const float* __restrict__ ssq_part, float* __restrict__ dsp) {
    int b = threadIdx.x;   // 32 threads
    float s = 0.f;
    for (int i = 0; i < 256; i++) s += ssq_part[i * 32 + b];
    dsp[b] = sqrtf((float)SPP / s + EPS);
}

// weight [co][ci][tap] fp32 -> wt4 fragment-contiguous bf16:
// [kc 8][tap 9][cog 16][lane 64][e 8], lane = kg*16+lcol:
//   co = cog*16 + (lane&15), ci = kc*32 + (lane>>4)*8 + e.
__global__ void k_wt(const float* __restrict__ weight, unsigned short* __restrict__ wt4) {
    int idx = blockIdx.x * 256 + threadIdx.x;   // grid 2304 -> 589824
    int e    = idx & 7;
    int r1   = idx >> 3;
    int lane = r1 & 63;
    int r2   = r1 >> 6;
    int cog  = r2 & 15;
    int r3   = r2 >> 4;       // 0..71
    int tap  = r3 % 9;
    int kc   = r3 / 9;
    int co = cog * 16 + (lane & 15);
    int ci = kc * 32 + (lane >> 4) * 8 + e;
    wt4[idx] = f2bf(weight[(co * 256 + ci) * 9 + tap]);
}

// x [b][ci][p] fp32 -> xs_t[b][p][ci] bf16 scaled by style[b][ci].
// LDS-tiled transpose, coalesced both sides.
__global__ __launch_bounds__(256) void k_xt(
    const float* __restrict__ x, const float* __restrict__ style,
    unsigned short* __restrict__ xst) {
    __shared__ float tile[64][65];
    int bid = blockIdx.x;
    int b  = (bid & 7) * 4 + ((bid >> 3) & 3);
    int p0 = (bid >> 5) * 64;
    int t = threadIdx.x;
    int w = t >> 6, lane = t & 63;
    int hi = t >> 5, lo = t & 31;

    for (int cc = 0; cc < 4; cc++) {
#pragma unroll
        for (int it = 0; it < 16; it++) {
            int ci_l = it * 4 + w;
            int ci = cc * 64 + ci_l;
            float st = style[b * 256 + ci];
            tile[lane][ci_l] = x[((size_t)(b * 256 + ci)) * SPP + p0 + lane] * st;
        }
        __syncthreads();
#pragma unroll
        for (int it = 0; it < 8; it++) {
            int p_l = it * 8 + hi;
            unsigned pk = (unsigned)f2bf(tile[p_l][lo * 2])
                        | ((unsigned)f2bf(tile[p_l][lo * 2 + 1]) << 16);
            unsigned* dst = (unsigned*)xst + ((size_t)(b * SPP + p0 + p_l)) * 128 + cc * 32 + lo;
            *dst = pk;
        }
        __syncthreads();
    }
}

// ---------------- MFMA conv kernel (shared-slab: 64co x 256p blocks) ------
// grid 2048: bid -> [rq(4)][cos(2)][b_lo(2)][xcd(3)], b = xcd*4+b_lo,
// h0 = rq*4, cog0 = cos*4 (64-co slab). block 256 = 4 waves; wave w owns
// row h0+w (64 p), ALL waves share the SAME weight slab -> per-kc L2
// weight traffic per block drops 2 slabs->1 (MSHR-merged across waves,
// L1 serves repeats). r12 counters showed L2 weight fill (~288KB/CU/kc
// ~= 5.1k cyc) ~ MFMA wall (5.6k) and serialized at kc start -> 42% util.
// Inner loop / bulk 9-tap coalesced preload / swizzle byte-identical r12.
// x-tile: 6 rows x 66 cols = 396 slots x 64B = 24.75KB per buffer.

__global__ __launch_bounds__(256, 2) void k_conv_mfma(
    const unsigned short* __restrict__ xst,
    const unsigned short* __restrict__ wt4,
    const float* __restrict__ demod,
    const float* __restrict__ sp,
    const float* __restrict__ dsp,
    const unsigned short* __restrict__ zeropad,
    float* __restrict__ out)
{
    __shared__ union {
        char stage[2][25344];      // 2 x 396 slots x 64B (1584 16B-units each)
        float ep[4][2176];         // 4 waves x 32 rows x 68 floats (34816 B)
    } lds;
    __shared__ float demod_l[64];

    int bid = blockIdx.x;
    int xcd  = bid & 7;
    int b_lo = (bid >> 3) & 3;
    int cos  = (bid >> 5) & 3;
    int rq   = bid >> 7;           // 0..15
    int b  = xcd * 4 + b_lo;
    int h0 = rq * 4;
    int cog0 = cos * 4;
    int t = threadIdx.x;
    int w = t >> 6, lane = t & 63;
    int lcol = lane & 15, kg = lane >> 4;

    if (t < 64) demod_l[t] = demod[b * 256 + cos * 64 + t];

    const unsigned short* xb = xst + (size_t)b * SPP * 256;

    // per-thread DMA source pointers (kc advances source by 32 elements)
    const unsigned short* sbase[7];
#pragma unroll
    for (int it = 0; it < 7; it++) {
        int idx16 = t + it * 256;
        const unsigned short* s = zeropad;
        if (idx16 < 1584) {
            int slot = idx16 >> 2, j = idx16 & 3;
            int row = slot / 66, col = slot - row * 66;   // row 0..5
            int g = j ^ ((slot >> 1) & 3);     // inverse swizzle on source
            int gh = h0 + row - 1, gw = col - 1;
            if ((unsigned)gh < 64u && (unsigned)gw < 64u)
                s = xb + ((size_t)(gh * 64 + gw)) * 256 + g * 8;
        }
        sbase[it] = s;
    }

#define STAGE_DMA(BUF, KC) { _Pragma("unroll") \
    for (int it = 0; it < 6; it++) \
        dma16(sbase[it] + (KC) * 32, &lds.stage[BUF][0] + (t + it * 256) * 16); \
    if (t < 48) dma16(sbase[6] + (KC) * 32, &lds.stage[BUF][0] + (t + 1536) * 16); }

    STAGE_DMA(0, 0);

    f32x4 acc[4][4];
#pragma unroll
    for (int m = 0; m < 4; m++)
#pragma unroll
        for (int n = 0; n < 4; n++) acc[m][n] = (f32x4){0.f, 0.f, 0.f, 0.f};

    int cur = 0;
    __syncthreads();   // drain prologue DMA

    for (int kc = 0; kc < 8; kc++) {
        // ---- bulk weight preload: 36 coalesced 1KB loads, oldest in queue ----
        short8 wreg[9][4];
        {
            const unsigned short* wkc = wt4 + (size_t)(kc * 9) * 8192;
#pragma unroll
            for (int tap = 0; tap < 9; tap++)
#pragma unroll
                for (int m = 0; m < 4; m++)
                    wreg[tap][m] = *(const short8*)(wkc + (size_t)(tap * 16 + cog0 + m) * 512 + lane * 8);
        }
        if (kc < 7) STAGE_DMA(cur ^ 1, kc + 1);   // younger than all weight loads
        const char* lb = &lds.stage[cur][0];

#pragma unroll
        for (int tap = 0; tap < 9; tap++) {
            const int dh = tap / 3, dw = tap - dh * 3;
            int sbase0 = (w + dh) * 66 + dw + lcol;
            int q = (sbase0 >> 1) & 3;               // n*16 doesn't touch bits 1-2
            const char* lbp = lb + sbase0 * 64 + ((kg ^ q) << 4);
#pragma unroll
            for (int n = 0; n < 4; n++) {
                short8 bv = *(const short8*)(lbp + n * 1024);
#pragma unroll
                for (int m = 0; m < 4; m++)
                    acc[m][n] = __builtin_amdgcn_mfma_f32_16x16x32_bf16(wreg[tap][m], bv, acc[m][n], 0, 0, 0);
            }
        }

        __syncthreads();
        cur ^= 1;
    }

    // ---- epilogue: scale, per-wave LDS transpose, coalesced dwordx4 stores ----
    float dspb = dsp[b];
    int hout = h0 + w;
    float spn[4];
#pragma unroll
    for (int nn = 0; nn < 4; nn++)
        spn[nn] = sp[b * SPP + hout * 64 + nn * 16 + lcol] * dspb;

    float* ep = &lds.ep[w][0];
#pragma unroll
    for (int ch = 0; ch < 2; ch++) {          // 2 chunks of 32 co
#pragma unroll
        for (int mm = 0; mm < 2; mm++) {
#pragma unroll
            for (int r2 = 0; r2 < 4; r2++) {
                int lr = mm * 16 + kg * 4 + r2;
                float dm = demod_l[ch * 32 + lr] * CONV_SCALE;
#pragma unroll
                for (int nn = 0; nn < 4; nn++)
                    ep[lr * 68 + nn * 16 + lcol] =
                        acc[ch * 2 + mm][nn][r2] * dm * spn[nn];
            }
        }
#pragma unroll
        for (int i = 0; i < 8; i++) {
            int lr = i * 4 + kg;
            f32x4 v = *(const f32x4*)(ep + lr * 68 + lcol * 4);
            int co_g = cos * 64 + ch * 32 + lr;
            *(f32x4*)&out[((size_t)(b * 256 + co_g)) * SPP + hout * 64 + lcol * 4] = v;
        }
    }
}

// ---------------- legacy spatial (fallback path only) ----------------
__global__ void k_spatial(const float* __restrict__ style_in,
                          const float* __restrict__ sp_w,
                          const float* __restrict__ sp_b,
                          float* __restrict__ sp,
                          float* __restrict__ dsp) {
    __shared__ float s_in[SDIM];
    __shared__ float red[256];
    int b = blockIdx.x, t = threadIdx.x;
    s_in[t] = style_in[b * 512 + 256 + t];
    __syncthreads();
    float ss = 0.f;
    for (int i = 0; i < 16; i++) {
        int p = i * 256 + t;
        const float* wr = sp_w + p * SDIM;
        float acc = 0.f;
        for (int k = 0; k < 256; k++) acc += s_in[k] * wr[k];
        float v = acc * LIN_SCALE + sp_b[p];
        sp[b * SPP + p] = v;
        ss += v * v;
    }
    red[t] = ss; __syncthreads();
    for (int o = 128; o > 0; o >>= 1) { if (t < o) red[t] += red[t + o]; __syncthreads(); }
    if (t == 0) dsp[b] = sqrtf((float)SPP / red[0] + EPS);
}

// ---------------- fp32 fallback conv (round-1, known-good) ----------------

#define COTILE 16
#define TS 32
#define HALO 34
#define XS 36

__global__ __launch_bounds__(256) void k_conv_f32(
    const float* __restrict__ x, const float* __restrict__ weight,
    const float* __restrict__ style, const float* __restrict__ demod,
    const float* __restrict__ sp, const float* __restrict__ dsp,
    float* __restrict__ out) {
    __shared__ float xt[HALO * XS];
    __shared__ float wl[COTILE * 12];
    __shared__ float dml[COTILE];

    int bid = blockIdx.x;
    int tile = bid & 3;
    int cot = (bid >> 2) & 15;
    int b = bid >> 6;
    int h0 = (tile >> 1) * TS, w0 = (tile & 1) * TS;
    int t = threadIdx.x;
    int r = t >> 3;
    int cb = (t & 7) * 4;

    if (t < COTILE) dml[t] = demod[b * COUT + cot * COTILE + t];

    float acc[COTILE][4];
#pragma unroll
    for (int co = 0; co < COTILE; co++)
#pragma unroll
        for (int c = 0; c < 4; c++) acc[co][c] = 0.f;

    const float* xb = x + (size_t)b * CIN * SPP;
    const float* stb = style + b * CIN;

    for (int ci = 0; ci < CIN; ci++) {
        __syncthreads();
        const float* xc = xb + ci * SPP;
        for (int idx = t; idx < HALO * HALO; idx += 256) {
            int i = idx / HALO, j = idx - i * HALO;
            int h = h0 + i - 1, wv2 = w0 + j - 1;
            float v = 0.f;
            if ((unsigned)h < SPD && (unsigned)wv2 < SPD) v = xc[h * SPD + wv2];
            xt[i * XS + j] = v;
        }
        if (t < COTILE * 9) {
            int co = t / 9, tap = t - co * 9;
            float wv = weight[((cot * COTILE + co) * CIN + ci) * 9 + tap];
            wl[co * 12 + tap] = wv * (CONV_SCALE * stb[ci]) * dml[co];
        }
        __syncthreads();

        float xv[3][6];
#pragma unroll
        for (int dh = 0; dh < 3; dh++)
#pragma unroll
            for (int jj = 0; jj < 6; jj++)
                xv[dh][jj] = xt[(r + dh) * XS + cb + jj];

#pragma unroll
        for (int co = 0; co < COTILE; co++) {
            float w9[9];
#pragma unroll
            for (int q = 0; q < 9; q++) w9[q] = wl[co * 12 + q];
#pragma unroll
            for (int c = 0; c < 4; c++) {
                float a = acc[co][c];
#pragma unroll
                for (int dh = 0; dh < 3; dh++)
#pragma unroll
                    for (int dw = 0; dw < 3; dw++)
                        a += w9[dh * 3 + dw] * xv[dh][c + dw];
                acc[co][c] = a;
            }
        }
    }

    float dspb = dsp[b];
    int hh = h0 + r, ww = w0 + cb;
    const float* spb = sp + b * SPP + hh * SPD + ww;
    float m[4];
#pragma unroll
    for (int c = 0; c < 4; c++) m[c] = spb[c] * dspb;
#pragma unroll
    for (int co = 0; co < COTILE; co++) {
        float4 v = make_float4(acc[co][0] * m[0], acc[co][1] * m[1],
                               acc[co][2] * m[2], acc[co][3] * m[3]);
        *(float4*)&out[(size_t)((b * COUT + cot * COTILE + co) * SPP) + hh * SPD + ww] = v;
    }
}

// ---------------- launcher ----------------

extern "C" void kernel_launch(void* const* d_in, const int* in_sizes, int n_in,
                              void* d_out, int out_size, void* d_ws, size_t ws_size,
                              hipStream_t stream) {
    const float* x        = (const float*)d_in[0];
    const float* style_in = (const float*)d_in[1];
    const float* weight   = (const float*)d_in[2];
    const float* mod_w    = (const float*)d_in[3];
    const float* mod_b    = (const float*)d_in[4];
    const float* sp_w     = (const float*)d_in[5];
    const float* sp_b     = (const float*)d_in[6];
    float* out = (float*)d_out;
    char* wsb = (char*)d_ws;

    float* style = (float*)(wsb + WSB_STYLE);
    float* demod = (float*)(wsb + WSB_DEMOD);
    float* wsq   = (float*)(wsb + WSB_WSQ);
    float* sp    = (float*)(wsb + WSB_SP);
    float* dsp   = (float*)(wsb + WSB_DSP);
    float* ssqp  = (float*)(wsb + WSB_SSQP);
    unsigned short* wt4 = (unsigned short*)(wsb + WSB_WT2);
    unsigned short* xst = (unsigned short*)(wsb + WSB_XST);

    hipLaunchKernelGGL(k_wsq, dim3(COUT), dim3(CIN), 0, stream,
                       weight, wsq, (unsigned*)(wsb + WSB_ZERO));
    hipLaunchKernelGGL(k_style, dim3(BB), dim3(256), 0, stream,
                       style_in, mod_w, mod_b, wsq, style, demod);

    if (ws_size >= WS_NEED) {
        hipLaunchKernelGGL(k_spatial2, dim3(256), dim3(256), 0, stream,
                           style_in, sp_w, sp_b, sp, ssqp);
        hipLaunchKernelGGL(k_dsp, dim3(1), dim3(32), 0, stream, ssqp, dsp);
        hipLaunchKernelGGL(k_wt, dim3(2304), dim3(256), 0, stream, weight, wt4);
        hipLaunchKernelGGL(k_xt, dim3(2048), dim3(256), 0, stream, x, style, xst);
        hipLaunchKernelGGL(k_conv_mfma, dim3(2048), dim3(256), 0, stream,
                           xst, wt4, demod, sp, dsp,
                           (const unsigned short*)(wsb + WSB_ZERO), out);
    } else {
        hipLaunchKernelGGL(k_spatial, dim3(BB), dim3(256), 0, stream,
                           style_in, sp_w, sp_b, sp, dsp);
        hipLaunchKernelGGL(k_conv_f32, dim3(2048), dim3(256), 0, stream,
                           x, weight, style, demod, sp, dsp, out);
    }
}